// Round 1
// baseline (1534.887 us; speedup 1.0000x reference)
//
#include <hip/hip_runtime.h>
#include <stdint.h>

typedef short        s16x8 __attribute__((ext_vector_type(8)));
typedef float        f32x4 __attribute__((ext_vector_type(4)));
typedef unsigned int u32;
typedef unsigned short u16;

#define B_SZ   4
#define L_SZ   2048
#define NH     16
#define DH     64
#define DMODEL 1024
#define TOKENS (B_SZ * L_SZ)            /* 8192 */
#define FEAT_ELEMS (TOKENS * DMODEL)    /* 8,388,608 */

__device__ __forceinline__ u32 fbits(float f) { return __float_as_uint(f); }

// pack two floats -> bf16 pair (round-half-up): result = (bf(hi)<<16) | bf(lo)
__device__ __forceinline__ u32 pk_bf16(float lo, float hi) {
  return __builtin_amdgcn_perm(fbits(hi) + 0x8000u, fbits(lo) + 0x8000u, 0x07060302u);
}
__device__ __forceinline__ u16 bf16_1(float f) { return (u16)((fbits(f) + 0x8000u) >> 16); }

// ---------------- fp32 -> bf16 bulk convert ----------------
__global__ __launch_bounds__(256) void cvt_kernel(const float* __restrict__ in,
                                                  u16* __restrict__ out, int n4) {
  int i = blockIdx.x * 256 + threadIdx.x;
  if (i >= n4) return;
  const float4 v = ((const float4*)in)[i];
  uint2 o;
  o.x = pk_bf16(v.x, v.y);
  o.y = pk_bf16(v.z, v.w);
  ((uint2*)out)[i] = o;
}

// ---------------- bf16 GEMM: C[m][n] = sum_k A[m][k]*B[n][k] ----------------
// MODE 0: C bf16.  MODE 1: C fp32 = acc + resid[m*ldc+n] (fc + residual).
// grid = (M/128, N/128), block 256 (4 waves, each 64x64 = 4x4 MFMA tiles).
template<int MODE>
__global__ __launch_bounds__(256) void gemm_k(const u16* __restrict__ A,
                                              const u16* __restrict__ B,
                                              void* __restrict__ Cv,
                                              const float* __restrict__ resid,
                                              int lda, int ldb, int ldc, int K) {
  const int lane = threadIdx.x & 63;
  const int w    = threadIdx.x >> 6;
  const int lr = lane & 15, lq = lane >> 4;
  const int m_w = blockIdx.x * 128 + (w & 1) * 64;
  const int n_w = blockIdx.y * 128 + (w >> 1) * 64;

  size_t aoff[4], boff[4];
#pragma unroll
  for (int t = 0; t < 4; ++t) {
    aoff[t] = (size_t)(m_w + t * 16 + lr) * lda + lq * 8;
    boff[t] = (size_t)(n_w + t * 16 + lr) * ldb + lq * 8;
  }
  f32x4 acc[4][4] = {};

#pragma unroll 2
  for (int k0 = 0; k0 < K; k0 += 32) {
    s16x8 af[4], bfr[4];
#pragma unroll
    for (int t = 0; t < 4; ++t) af[t]  = *(const s16x8*)(A + aoff[t] + k0);
#pragma unroll
    for (int t = 0; t < 4; ++t) bfr[t] = *(const s16x8*)(B + boff[t] + k0);
#pragma unroll
    for (int mt = 0; mt < 4; ++mt)
#pragma unroll
      for (int nt = 0; nt < 4; ++nt)
        acc[mt][nt] = __builtin_amdgcn_mfma_f32_16x16x32_bf16(af[mt], bfr[nt], acc[mt][nt], 0, 0, 0);
  }

#pragma unroll
  for (int mt = 0; mt < 4; ++mt)
#pragma unroll
    for (int nt = 0; nt < 4; ++nt) {
      const int row0 = m_w + mt * 16 + lq * 4;
      const int col  = n_w + nt * 16 + lr;
#pragma unroll
      for (int i = 0; i < 4; ++i) {
        const float v = acc[mt][nt][i];
        const size_t idx = (size_t)(row0 + i) * ldc + col;
        if (MODE == 0) ((u16*)Cv)[idx] = bf16_1(v);
        else           ((float*)Cv)[idx] = v + resid[idx];
      }
    }
}

// ---------------- fused attention ----------------
// One wave = 32 q-rows of one (b,h).  grid = B*NH*(L/128) blocks of 256.
// Loop 1: l = row-sums of exp(S/8) (register-resident, shuffle reduce).
// Loop 2: recompute S, P = exp/l, stage fp32 P in per-wave LDS, write attn
//         coalesced, read back bf16 A-frags, O += P @ V.
__global__ __launch_bounds__(256) void attn_k(const u16* __restrict__ eh,
                                              const u16* __restrict__ xht,
                                              float* __restrict__ attn,
                                              u16* __restrict__ feat) {
  __shared__ float plds[4][32 * 68];
  const int lane = threadIdx.x & 63;
  const int w = threadIdx.x >> 6;
  const int lr = lane & 15, lq = lane >> 4;
  const int qt = blockIdx.x & 15;
  const int bh = blockIdx.x >> 4;
  const int b = bh >> 4, h = bh & 15;
  const int q0 = qt * 128 + w * 32;
  float* P = plds[w];

  // Q fragments: A-layout, live in registers for the whole kernel
  s16x8 qf[2][2];
#pragma unroll
  for (int mt = 0; mt < 2; ++mt)
#pragma unroll
    for (int ks = 0; ks < 2; ++ks)
      qf[mt][ks] = *(const s16x8*)(eh + (size_t)(b * L_SZ + q0 + mt * 16 + lr) * DMODEL
                                      + h * DH + ks * 32 + lq * 8);

  // ---- loop 1: denominators ----
  float lsum[2][4] = {};
#pragma unroll 1
  for (int nc = 0; nc < 32; ++nc) {
    const int kb = nc * 64;
    s16x8 kf[4][2];
#pragma unroll
    for (int nt = 0; nt < 4; ++nt)
#pragma unroll
      for (int ks = 0; ks < 2; ++ks)
        kf[nt][ks] = *(const s16x8*)(eh + (size_t)(b * L_SZ + kb + nt * 16 + lr) * DMODEL
                                        + h * DH + ks * 32 + lq * 8);
    f32x4 s[2][4] = {};
#pragma unroll
    for (int mt = 0; mt < 2; ++mt)
#pragma unroll
      for (int nt = 0; nt < 4; ++nt) {
        s[mt][nt] = __builtin_amdgcn_mfma_f32_16x16x32_bf16(qf[mt][0], kf[nt][0], s[mt][nt], 0, 0, 0);
        s[mt][nt] = __builtin_amdgcn_mfma_f32_16x16x32_bf16(qf[mt][1], kf[nt][1], s[mt][nt], 0, 0, 0);
      }
#pragma unroll
    for (int mt = 0; mt < 2; ++mt)
#pragma unroll
      for (int i = 0; i < 4; ++i) {
        float rp = __expf(s[mt][0][i] * 0.125f) + __expf(s[mt][1][i] * 0.125f)
                 + __expf(s[mt][2][i] * 0.125f) + __expf(s[mt][3][i] * 0.125f);
        rp += __shfl_xor(rp, 1);
        rp += __shfl_xor(rp, 2);
        rp += __shfl_xor(rp, 4);
        rp += __shfl_xor(rp, 8);
        lsum[mt][i] += rp;
      }
  }
  float rl[2][4];
#pragma unroll
  for (int mt = 0; mt < 2; ++mt)
#pragma unroll
    for (int i = 0; i < 4; ++i) rl[mt][i] = 1.0f / lsum[mt][i];

  // ---- loop 2: attn write + O accumulate ----
  f32x4 o[2][4] = {};
  float* attn_base = attn + ((size_t)bh * L_SZ + q0) * L_SZ;

#pragma unroll 1
  for (int nc = 0; nc < 32; ++nc) {
    const int kb = nc * 64;
    s16x8 kf[4][2];
#pragma unroll
    for (int nt = 0; nt < 4; ++nt)
#pragma unroll
      for (int ks = 0; ks < 2; ++ks)
        kf[nt][ks] = *(const s16x8*)(eh + (size_t)(b * L_SZ + kb + nt * 16 + lr) * DMODEL
                                        + h * DH + ks * 32 + lq * 8);
    f32x4 s[2][4] = {};
#pragma unroll
    for (int mt = 0; mt < 2; ++mt)
#pragma unroll
      for (int nt = 0; nt < 4; ++nt) {
        s[mt][nt] = __builtin_amdgcn_mfma_f32_16x16x32_bf16(qf[mt][0], kf[nt][0], s[mt][nt], 0, 0, 0);
        s[mt][nt] = __builtin_amdgcn_mfma_f32_16x16x32_bf16(qf[mt][1], kf[nt][1], s[mt][nt], 0, 0, 0);
      }

    // keep this iteration's ds_writes below the previous iteration's ds_reads
    __asm__ volatile("" ::: "memory");
#pragma unroll
    for (int mt = 0; mt < 2; ++mt)
#pragma unroll
      for (int nt = 0; nt < 4; ++nt)
#pragma unroll
        for (int i = 0; i < 4; ++i) {
          const float p = __expf(s[mt][nt][i] * 0.125f) * rl[mt][i];
          P[(mt * 16 + lq * 4 + i) * 68 + nt * 16 + lr] = p;
        }
    __asm__ volatile("s_waitcnt lgkmcnt(0)" ::: "memory");

    // coalesced attn store (fp32) from LDS: 4 rows x 256B per instruction
#pragma unroll
    for (int jj = 0; jj < 8; ++jj) {
      const int fi = jj * 64 + lane;
      const int row = fi >> 4, c4 = (fi & 15) * 4;
      f32x4 v = *(const f32x4*)(P + row * 68 + c4);
      __builtin_nontemporal_store(v, (f32x4*)(attn_base + (size_t)row * L_SZ + kb + c4));
    }

    // P in A-operand layout, packed to bf16
    s16x8 pf[2][2];
#pragma unroll
    for (int mt = 0; mt < 2; ++mt)
#pragma unroll
      for (int ks = 0; ks < 2; ++ks) {
        const float* pp = P + (mt * 16 + lr) * 68 + ks * 32 + lq * 8;
        f32x4 x0 = *(const f32x4*)pp;
        f32x4 x1 = *(const f32x4*)(pp + 4);
        union { u32 d[4]; s16x8 v; } u;
        u.d[0] = pk_bf16(x0[0], x0[1]);
        u.d[1] = pk_bf16(x0[2], x0[3]);
        u.d[2] = pk_bf16(x1[0], x1[1]);
        u.d[3] = pk_bf16(x1[2], x1[3]);
        pf[mt][ks] = u.v;
      }

    // V fragments from transposed xh: rows are [d][token], contiguous in key
    s16x8 vf[4][2];
#pragma unroll
    for (int nt = 0; nt < 4; ++nt)
#pragma unroll
      for (int ks = 0; ks < 2; ++ks)
        vf[nt][ks] = *(const s16x8*)(xht + (size_t)(h * DH + nt * 16 + lr) * TOKENS
                                         + b * L_SZ + kb + ks * 32 + lq * 8);
#pragma unroll
    for (int mt = 0; mt < 2; ++mt)
#pragma unroll
      for (int nt = 0; nt < 4; ++nt) {
        o[mt][nt] = __builtin_amdgcn_mfma_f32_16x16x32_bf16(pf[mt][0], vf[nt][0], o[mt][nt], 0, 0, 0);
        o[mt][nt] = __builtin_amdgcn_mfma_f32_16x16x32_bf16(pf[mt][1], vf[nt][1], o[mt][nt], 0, 0, 0);
      }
  }

  // feat store: [token][h*64+d], bf16
#pragma unroll
  for (int mt = 0; mt < 2; ++mt)
#pragma unroll
    for (int nt = 0; nt < 4; ++nt) {
      const int trow = b * L_SZ + q0 + mt * 16 + lq * 4;
      const int col  = h * DH + nt * 16 + lr;
#pragma unroll
      for (int i = 0; i < 4; ++i)
        feat[(size_t)(trow + i) * DMODEL + col] = bf16_1(o[mt][nt][i]);
    }
}

// ---------------- LayerNorm (in-place on d_out feat region) ----------------
__global__ __launch_bounds__(256) void ln_k(float* __restrict__ io,
                                            const float* __restrict__ gamma,
                                            const float* __restrict__ beta) {
  const int row = blockIdx.x;
  const int tid = threadIdx.x;
  const int lane = tid & 63, w = tid >> 6;
  float4 v = *(const float4*)(io + (size_t)row * DMODEL + tid * 4);
  float s  = v.x + v.y + v.z + v.w;
  float s2 = v.x * v.x + v.y * v.y + v.z * v.z + v.w * v.w;
#pragma unroll
  for (int off = 1; off < 64; off <<= 1) {
    s  += __shfl_xor(s, off);
    s2 += __shfl_xor(s2, off);
  }
  __shared__ float rs[4], rq[4];
  if (lane == 0) { rs[w] = s; rq[w] = s2; }
  __syncthreads();
  s  = rs[0] + rs[1] + rs[2] + rs[3];
  s2 = rq[0] + rq[1] + rq[2] + rq[3];
  const float mean = s * (1.0f / DMODEL);
  const float var  = s2 * (1.0f / DMODEL) - mean * mean;
  const float rstd = rsqrtf(var + 1e-6f);
  const float4 g  = *(const float4*)(gamma + tid * 4);
  const float4 bb = *(const float4*)(beta + tid * 4);
  float4 o;
  o.x = (v.x - mean) * rstd * g.x + bb.x;
  o.y = (v.y - mean) * rstd * g.y + bb.y;
  o.z = (v.z - mean) * rstd * g.z + bb.z;
  o.w = (v.w - mean) * rstd * g.w + bb.w;
  *(float4*)(io + (size_t)row * DMODEL + tid * 4) = o;
}

// ---------------- launch ----------------
// Workspace layout (bytes), total 88 MiB (assumes ws_size >= 92,274,688):
//   [0,16M)   e_bf16      [16M,32M) x_bf16
//   [32M,34M) We_bf16     [34M,36M) Wx_bf16   [36M,38M) Wfc_bf16
//   [40M,56M) eh   bf16 [8192][1024]
//   [56M,72M) xh_t bf16 [1024][8192]  (transposed so PV B-frags are contiguous)
//   [72M,88M) feat bf16 [8192][1024]
extern "C" void kernel_launch(void* const* d_in, const int* in_sizes, int n_in,
                              void* d_out, int out_size, void* d_ws, size_t ws_size,
                              hipStream_t stream) {
  const float* e     = (const float*)d_in[0];
  const float* x     = (const float*)d_in[1];
  const float* We    = (const float*)d_in[2];
  const float* Wx    = (const float*)d_in[3];
  const float* Wfc   = (const float*)d_in[4];
  const float* gamma = (const float*)d_in[5];
  const float* beta  = (const float*)d_in[6];

  float* out  = (float*)d_out;
  float* attn = out + (size_t)FEAT_ELEMS;

  char* ws = (char*)d_ws;
  const size_t MB = 1024 * 1024;
  u16* e_bf   = (u16*)(ws + 0 * MB);
  u16* x_bf   = (u16*)(ws + 16 * MB);
  u16* we_bf  = (u16*)(ws + 32 * MB);
  u16* wx_bf  = (u16*)(ws + 34 * MB);
  u16* wfc_bf = (u16*)(ws + 36 * MB);
  u16* eh     = (u16*)(ws + 40 * MB);
  u16* xht    = (u16*)(ws + 56 * MB);
  u16* feat   = (u16*)(ws + 72 * MB);

  cvt_kernel<<<8192, 256, 0, stream>>>(e, e_bf, FEAT_ELEMS / 4);
  cvt_kernel<<<8192, 256, 0, stream>>>(x, x_bf, FEAT_ELEMS / 4);
  cvt_kernel<<<1024, 256, 0, stream>>>(We,  we_bf,  (DMODEL * DMODEL) / 4);
  cvt_kernel<<<1024, 256, 0, stream>>>(Wx,  wx_bf,  (DMODEL * DMODEL) / 4);
  cvt_kernel<<<1024, 256, 0, stream>>>(Wfc, wfc_bf, (DMODEL * DMODEL) / 4);

  // eh[t][c] = e . We^T
  gemm_k<0><<<dim3(TOKENS / 128, DMODEL / 128), 256, 0, stream>>>(
      e_bf, we_bf, eh, nullptr, DMODEL, DMODEL, DMODEL, DMODEL);
  // xh_t[c][t] = Wx . x^T   (transposed projection)
  gemm_k<0><<<dim3(DMODEL / 128, TOKENS / 128), 256, 0, stream>>>(
      wx_bf, x_bf, xht, nullptr, DMODEL, DMODEL, TOKENS, DMODEL);

  attn_k<<<B_SZ * NH * (L_SZ / 128), 256, 0, stream>>>(eh, xht, attn, feat);

  // fc + residual -> d_out (pre-LN, fp32)
  gemm_k<1><<<dim3(TOKENS / 128, DMODEL / 128), 256, 0, stream>>>(
      feat, wfc_bf, out, x, DMODEL, DMODEL, DMODEL, DMODEL);

  ln_k<<<TOKENS, 256, 0, stream>>>(out, gamma, beta);
}